// Round 1
// baseline (607.933 us; speedup 1.0000x reference)
//
#include <hip/hip_runtime.h>

// 2-layer GCNConv, N=500K, E=16M, Cin=1, Cout=4, fp32.
//
// Round-6: k_reduce2 (119us) was DS-pipe bound: the 64-lane segmented
// shuffle-scan costs ~39 ds_bpermute/atomic ops per 64 edges (~73us of
// LDS-pipe serialization, invisible in VALUBusy/HBM counters). k_sort
// already emits exact per-node offsets (off_g), so the scan is
// unnecessary: new reduce kernels assign a 4-lane quad per node
// (deg mean=32 -> ~8 strided iters), accumulate messages in registers,
// and reduce with 2 __shfl_xor per node. Zero LDS, zero atomics,
// coalesced per-lane output stores.

#define B1_BLOCKS 512
#define B1_THREADS 1024
#define TILE1 16384
#define B2_THREADS 1024
#define TILE2 16384
#define MAXNB1 256       // coarse buckets (2048 nodes); needs n <= 524288
#define SORT_STAGE 12032 // ints staged in LDS by k_sort; C2 <= this
// fallback (round-5 flat binning) constants
#define FB_BLOCKS 512
#define FB_THREADS 1024
#define FB_PAD 8
#define MAXNBF 2048

// ---------------- pass 1: coarse split (LDS-staged, coalesced flush) -------
__global__ __launch_bounds__(B1_THREADS) void k_bin1(
    const int* __restrict__ src, const int* __restrict__ dst, int E,
    int chunk, int nb1, int C1, int* __restrict__ gcur1,
    int* __restrict__ pay1) {
  __shared__ int out[TILE1];
  __shared__ int hist[MAXNB1], toff[MAXNB1], wcur[MAXNB1], gb[MAXNB1];
  __shared__ int sbuf[2][MAXNB1];
  const int tid = threadIdx.x;
  const long long e0 = (long long)blockIdx.x * chunk;
  long long reml = (long long)E - e0;
  const int lim = reml < 0 ? 0 : (reml < chunk ? (int)reml : chunk);
  const int* dch = dst + e0;
  const int* sch = src + e0;

  for (int tb = 0; tb < lim; tb += TILE1) {
    const int tcnt = min(TILE1, lim - tb);
    const int nv = tcnt >> 2;
    for (int j = tid; j < MAXNB1; j += B1_THREADS) hist[j] = 0;
    __syncthreads();

    // phase A: tile histogram of coarse keys
    const int* dt = dch + tb;
    for (int k = tid; k < nv; k += B1_THREADS) {
      int4 d = reinterpret_cast<const int4*>(dt)[k];
      atomicAdd(&hist[d.x >> 11], 1);
      atomicAdd(&hist[d.y >> 11], 1);
      atomicAdd(&hist[d.z >> 11], 1);
      atomicAdd(&hist[d.w >> 11], 1);
    }
    for (int k = (nv << 2) + tid; k < tcnt; k += B1_THREADS)
      atomicAdd(&hist[dt[k] >> 11], 1);
    __syncthreads();

    // phase B: exclusive scan (256-wide) + exact global range reservation
    if (tid < MAXNB1) sbuf[0][tid] = hist[tid];
    __syncthreads();
    int pi = 0;
    for (int dd = 1; dd < MAXNB1; dd <<= 1) {
      if (tid < MAXNB1) {
        int v = sbuf[pi][tid];
        if (tid >= dd) v += sbuf[pi][tid - dd];
        sbuf[pi ^ 1][tid] = v;
      }
      pi ^= 1;
      __syncthreads();
    }
    if (tid < MAXNB1) {
      int c = hist[tid];
      int exc = sbuf[pi][tid] - c;
      toff[tid] = exc;
      wcur[tid] = exc;
      gb[tid] = c ? atomicAdd(&gcur1[tid], c) : 0;
    }
    __syncthreads();

    // phase C: rank + place packed (src<<11 | dst&2047) into LDS out
    const int* st = sch + tb;
    for (int k = tid; k < nv; k += B1_THREADS) {
      int4 d = reinterpret_cast<const int4*>(dt)[k];
      int4 s = reinterpret_cast<const int4*>(st)[k];
      int r0 = atomicAdd(&wcur[d.x >> 11], 1);
      int r1 = atomicAdd(&wcur[d.y >> 11], 1);
      int r2 = atomicAdd(&wcur[d.z >> 11], 1);
      int r3 = atomicAdd(&wcur[d.w >> 11], 1);
      out[r0] = (s.x << 11) | (d.x & 2047);
      out[r1] = (s.y << 11) | (d.y & 2047);
      out[r2] = (s.z << 11) | (d.z & 2047);
      out[r3] = (s.w << 11) | (d.w & 2047);
    }
    for (int k = (nv << 2) + tid; k < tcnt; k += B1_THREADS) {
      int d = dt[k], s = st[k];
      int r = atomicAdd(&wcur[d >> 11], 1);
      out[r] = (s << 11) | (d & 2047);
    }
    __syncthreads();

    // phase D: wave-per-bucket coalesced copy LDS -> global
    const int wv = tid >> 6, lane = tid & 63;
    for (int j = wv; j < nb1; j += 16) {
      const int c = wcur[j] - toff[j];
      if (!c) continue;
      const int gbase = gb[j];
      const long long pbase = (long long)j * C1;
      for (int q = lane; q < c; q += 64) {
        int gi = gbase + q;
        if (gi < C1) pay1[pbase + gi] = out[toff[j] + q];
      }
    }
    __syncthreads();
  }
}

// ---------------- pass 2: fine split (8 buckets per coarse) ----------------
__global__ __launch_bounds__(B2_THREADS) void k_bin2(
    const int* __restrict__ pay1, const int* __restrict__ gcur1, int C1,
    int C2, int* __restrict__ gcur2, int* __restrict__ pay2) {
  __shared__ int out[TILE2];
  __shared__ int hist[8], toff9[9], wcur[8], gb[8];
  const int cb = blockIdx.x >> 1;
  const int half = blockIdx.x & 1;
  const int tid = threadIdx.x;
  const int Lc = min(gcur1[cb], C1);
  int mid = ((Lc >> 1) + 3) & ~3;
  if (mid > Lc) mid = Lc;
  const int h0 = half ? mid : 0;
  const int h1 = half ? Lc : mid;
  const int* seg = pay1 + (long long)cb * C1;

  for (int tb = h0; tb < h1; tb += TILE2) {
    const int tcnt = min(TILE2, h1 - tb);
    const int nv = tcnt >> 2;
    if (tid < 8) hist[tid] = 0;
    __syncthreads();
    const int* pt = seg + tb;

    for (int k = tid; k < nv; k += B2_THREADS) {
      int4 p = reinterpret_cast<const int4*>(pt)[k];
      atomicAdd(&hist[(p.x >> 8) & 7], 1);
      atomicAdd(&hist[(p.y >> 8) & 7], 1);
      atomicAdd(&hist[(p.z >> 8) & 7], 1);
      atomicAdd(&hist[(p.w >> 8) & 7], 1);
    }
    for (int k = (nv << 2) + tid; k < tcnt; k += B2_THREADS)
      atomicAdd(&hist[(pt[k] >> 8) & 7], 1);
    __syncthreads();

    if (tid == 0) {
      int run = 0;
      for (int j = 0; j < 8; ++j) { toff9[j] = run; run += hist[j]; }
      toff9[8] = run;
    }
    __syncthreads();
    if (tid < 8) {
      wcur[tid] = toff9[tid];
      gb[tid] = hist[tid] ? atomicAdd(&gcur2[cb * 8 + tid], hist[tid]) : 0;
    }
    __syncthreads();

    for (int k = tid; k < nv; k += B2_THREADS) {
      int4 p = reinterpret_cast<const int4*>(pt)[k];
      out[atomicAdd(&wcur[(p.x >> 8) & 7], 1)] = ((p.x >> 11) << 8) | (p.x & 255);
      out[atomicAdd(&wcur[(p.y >> 8) & 7], 1)] = ((p.y >> 11) << 8) | (p.y & 255);
      out[atomicAdd(&wcur[(p.z >> 8) & 7], 1)] = ((p.z >> 11) << 8) | (p.z & 255);
      out[atomicAdd(&wcur[(p.w >> 8) & 7], 1)] = ((p.w >> 11) << 8) | (p.w & 255);
    }
    for (int k = (nv << 2) + tid; k < tcnt; k += B2_THREADS) {
      int p = pt[k];
      out[atomicAdd(&wcur[(p >> 8) & 7], 1)] = ((p >> 11) << 8) | (p & 255);
    }
    __syncthreads();

    const int total = toff9[8];
    for (int q = tid; q < total; q += B2_THREADS) {
      int j = (q >= toff9[4]) ? 4 : 0;
      j += (q >= toff9[j + 2]) ? 2 : 0;
      j += (q >= toff9[j + 1]) ? 1 : 0;
      int o = gb[j] + (q - toff9[j]);
      if (o < C2) pay2[(long long)(cb * 8 + j) * C2 + o] = out[q];
    }
    __syncthreads();
  }
}

// ---------------- fallback flat binning (round-5, proven) ------------------
__global__ __launch_bounds__(FB_THREADS) void k_bin_flat(
    const int* __restrict__ src, const int* __restrict__ dst, int E,
    int chunk, int nbf, int C, int* __restrict__ gcur,
    int* __restrict__ payload) {
  __shared__ int hist[MAXNBF];
  __shared__ int lbase[MAXNBF];
  const int tid = threadIdx.x;
  const long long e0 = (long long)blockIdx.x * chunk;
  long long rem = (long long)E - e0;
  int lim = rem < 0 ? 0 : (rem < chunk ? (int)rem : chunk);
  for (int j = tid; j < nbf; j += FB_THREADS) hist[j] = 0;
  __syncthreads();
  const int* dch = dst + e0;
  const int* sch = src + e0;
  const int nv = lim >> 2;
  for (int k = tid; k < nv; k += FB_THREADS) {
    int4 d = reinterpret_cast<const int4*>(dch)[k];
    atomicAdd(&hist[d.x >> 8], 1);
    atomicAdd(&hist[d.y >> 8], 1);
    atomicAdd(&hist[d.z >> 8], 1);
    atomicAdd(&hist[d.w >> 8], 1);
  }
  for (int k = (nv << 2) + tid; k < lim; k += FB_THREADS)
    atomicAdd(&hist[dch[k] >> 8], 1);
  __syncthreads();
  for (int j = tid; j < nbf; j += FB_THREADS) {
    int c = hist[j];
    lbase[j] = c ? atomicAdd(&gcur[j], (c + FB_PAD - 1) & ~(FB_PAD - 1)) : 0;
    hist[j] = 0;
  }
  __syncthreads();
  for (int k = tid; k < nv; k += FB_THREADS) {
    int4 d = reinterpret_cast<const int4*>(dch)[k];
    int4 s = reinterpret_cast<const int4*>(sch)[k];
    int b0 = d.x >> 8, b1 = d.y >> 8, b2 = d.z >> 8, b3 = d.w >> 8;
    int r0 = atomicAdd(&hist[b0], 1) + lbase[b0];
    int r1 = atomicAdd(&hist[b1], 1) + lbase[b1];
    int r2 = atomicAdd(&hist[b2], 1) + lbase[b2];
    int r3 = atomicAdd(&hist[b3], 1) + lbase[b3];
    if (r0 < C) payload[(long long)b0 * C + r0] = (s.x << 8) | (d.x & 255);
    if (r1 < C) payload[(long long)b1 * C + r1] = (s.y << 8) | (d.y & 255);
    if (r2 < C) payload[(long long)b2 * C + r2] = (s.z << 8) | (d.z & 255);
    if (r3 < C) payload[(long long)b3 * C + r3] = (s.w << 8) | (d.w & 255);
  }
  for (int k = (nv << 2) + tid; k < lim; k += FB_THREADS) {
    int d = dch[k], s = sch[k];
    int bk = d >> 8;
    int r = atomicAdd(&hist[bk], 1) + lbase[bk];
    if (r < C) payload[(long long)bk * C + r] = (s << 8) | (d & 255);
  }
  __syncthreads();
  for (int j = tid; j < nbf; j += FB_THREADS) {
    int c = hist[j];
    if (c) {
      int pc = (c + FB_PAD - 1) & ~(FB_PAD - 1);
      long long base = (long long)j * C;
      for (int k = lbase[j] + c; k < lbase[j] + pc; ++k)
        if (k < C) payload[base + k] = -1;
    }
  }
}

// ---------------- per-bucket counting sort to node order -------------------
__global__ __launch_bounds__(256) void k_sort(
    int* __restrict__ payload, const int* __restrict__ gcur, int C,
    int n, const float* __restrict__ x,
    int* __restrict__ off_g, float* __restrict__ y) {
  __shared__ int stage[SORT_STAGE];
  __shared__ int hist[256];
  __shared__ int sbuf[2][256];
  __shared__ int cur[256];
  const int b = blockIdx.x, t = threadIdx.x;
  hist[t] = 0;
  __syncthreads();
  int* seg = payload + (long long)b * C;
  const int L = min(gcur[b], C);
  const int nv = L >> 2;
#pragma unroll 2
  for (int k = t; k < nv; k += 256) {
    int4 p = reinterpret_cast<const int4*>(seg)[k];
    reinterpret_cast<int4*>(stage)[k] = p;
    if (p.x >= 0) atomicAdd(&hist[p.x & 255], 1);
    if (p.y >= 0) atomicAdd(&hist[p.y & 255], 1);
    if (p.z >= 0) atomicAdd(&hist[p.z & 255], 1);
    if (p.w >= 0) atomicAdd(&hist[p.w & 255], 1);
  }
  for (int k = (nv << 2) + t; k < L; k += 256) {
    int p = seg[k];
    stage[k] = p;
    if (p >= 0) atomicAdd(&hist[p & 255], 1);
  }
  __syncthreads();
  sbuf[0][t] = hist[t];
  __syncthreads();
  int pi = 0;
  for (int d = 1; d < 256; d <<= 1) {
    int v = sbuf[pi][t];
    if (t >= d) v += sbuf[pi][t - d];
    sbuf[pi ^ 1][t] = v;
    pi ^= 1;
    __syncthreads();
  }
  const int inc = sbuf[pi][t];
  const int exc = inc - hist[t];
  cur[t] = exc;
  off_g[b * 257 + t] = exc;
  if (t == 255) off_g[b * 257 + 256] = inc;
  const int i = (b << 8) + t;
  if (i < n) y[i] = rsqrtf((float)(hist[t] + 1)) * x[i];
  __syncthreads();
#pragma unroll 4
  for (int k = t; k < L; k += 256) {
    int p = stage[k];
    if (p >= 0) {
      int pos = atomicAdd(&cur[p & 255], 1);
      seg[pos] = p;
    }
  }
}

// ---------------- layer-1: per-node quad-serial sum -> ds = (dinv, s) ------
// 4-lane quad owns one node; segment offsets come from off_g (k_sort).
// No shuffle-scan, no LDS, no atomics. Lane t ends holding node (b<<8)+t.
__global__ __launch_bounds__(256) void k_reduce1(
    const int* __restrict__ payload, const int* __restrict__ off_g, int C,
    int n, const float* __restrict__ y, float2* __restrict__ ds) {
  const int b = blockIdx.x, t = threadIdx.x;
  const int g = t >> 2, lane4 = t & 3;
  const int* seg = payload + (long long)b * C;
  const int* off = off_g + b * 257;
  float keep = 0.0f;
#pragma unroll
  for (int j = 0; j < 4; ++j) {
    const int m = (g << 2) | j;
    const int o0 = off[m], o1 = off[m + 1];
    float acc = 0.0f;
    for (int k = o0 + lane4; k < o1; k += 4)
      acc += y[seg[k] >> 8];
    acc += __shfl_xor(acc, 1, 4);
    acc += __shfl_xor(acc, 2, 4);
    if (j == lane4) keep = acc;  // node m == t for this lane
  }
  const int i = (b << 8) + t;
  if (i < n) {
    const int deg = off[t + 1] - off[t];
    const float r = rsqrtf((float)(deg + 1));
    ds[i] = make_float2(r, r * (keep + y[i]));  // coalesced float2 store
  }
}

// ---------------- layer-2: per-node quad-serial message sum ----------------
__global__ __launch_bounds__(256) void k_reduce2(
    const int* __restrict__ payload, const int* __restrict__ off_g, int C,
    int n, const float2* __restrict__ ds,
    const float* __restrict__ W1, const float* __restrict__ b1,
    const float* __restrict__ W2, const float* __restrict__ b2,
    float4* __restrict__ out) {
  const int b = blockIdx.x, t = threadIdx.x;
  const int g = t >> 2, lane4 = t & 3;
  const float w10 = W1[0], w11 = W1[1], w12 = W1[2], w13 = W1[3];
  const float c10 = b1[0], c11 = b1[1], c12 = b1[2], c13 = b1[3];
  float w2[16];
#pragma unroll
  for (int k = 0; k < 16; ++k) w2[k] = W2[k];
  const int* seg = payload + (long long)b * C;
  const int* off = off_g + b * 257;
  float kx = 0.f, ky = 0.f, kz = 0.f, kw = 0.f;
#pragma unroll
  for (int j = 0; j < 4; ++j) {
    const int m = (g << 2) | j;
    const int o0 = off[m], o1 = off[m + 1];
    float gx = 0.f, gy = 0.f, gz = 0.f, gw = 0.f;
    for (int k = o0 + lane4; k < o1; k += 4) {
      const int p = seg[k];
      const float2 v = ds[p >> 8];
      const float r = v.x, s = v.y;
      const float h0 = fmaxf(fmaf(s, w10, c10), 0.f);
      const float h1 = fmaxf(fmaf(s, w11, c11), 0.f);
      const float h2 = fmaxf(fmaf(s, w12, c12), 0.f);
      const float h3 = fmaxf(fmaf(s, w13, c13), 0.f);
      gx += r * (h0 * w2[0] + h1 * w2[4] + h2 * w2[8]  + h3 * w2[12]);
      gy += r * (h0 * w2[1] + h1 * w2[5] + h2 * w2[9]  + h3 * w2[13]);
      gz += r * (h0 * w2[2] + h1 * w2[6] + h2 * w2[10] + h3 * w2[14]);
      gw += r * (h0 * w2[3] + h1 * w2[7] + h2 * w2[11] + h3 * w2[15]);
    }
    gx += __shfl_xor(gx, 1, 4);
    gx += __shfl_xor(gx, 2, 4);
    gy += __shfl_xor(gy, 1, 4);
    gy += __shfl_xor(gy, 2, 4);
    gz += __shfl_xor(gz, 1, 4);
    gz += __shfl_xor(gz, 2, 4);
    gw += __shfl_xor(gw, 1, 4);
    gw += __shfl_xor(gw, 2, 4);
    if (j == lane4) { kx = gx; ky = gy; kz = gz; kw = gw; }
  }
  const int i = (b << 8) + t;
  if (i < n) {
    const float2 v = ds[i];
    const float r = v.x, s = v.y;
    const float h0 = fmaxf(fmaf(s, w10, c10), 0.f);
    const float h1 = fmaxf(fmaf(s, w11, c11), 0.f);
    const float h2 = fmaxf(fmaf(s, w12, c12), 0.f);
    const float h3 = fmaxf(fmaf(s, w13, c13), 0.f);
    const float sx = r * (h0 * w2[0] + h1 * w2[4] + h2 * w2[8]  + h3 * w2[12]);
    const float sy = r * (h0 * w2[1] + h1 * w2[5] + h2 * w2[9]  + h3 * w2[13]);
    const float sz = r * (h0 * w2[2] + h1 * w2[6] + h2 * w2[10] + h3 * w2[14]);
    const float sw = r * (h0 * w2[3] + h1 * w2[7] + h2 * w2[11] + h3 * w2[15]);
    out[i] = make_float4(b2[0] + r * (kx + sx),
                         b2[1] + r * (ky + sy),
                         b2[2] + r * (kz + sz),
                         b2[3] + r * (kw + sw));  // coalesced float4 store
  }
}

extern "C" void kernel_launch(void* const* d_in, const int* in_sizes, int n_in,
                              void* d_out, int out_size, void* d_ws, size_t ws_size,
                              hipStream_t stream) {
  const float* x  = (const float*)d_in[0];
  const int*   ei = (const int*)d_in[1];
  const float* W1 = (const float*)d_in[2];
  const float* b1 = (const float*)d_in[3];
  const float* W2 = (const float*)d_in[4];
  const float* b2 = (const float*)d_in[5];

  const int n = in_sizes[0];
  const int E = in_sizes[1] / 2;
  const int* src = ei;
  const int* dst = ei + E;

  const int nbf = (n + 255) >> 8;    // fine buckets (256 nodes)
  const int nb1 = (n + 2047) >> 11;  // coarse buckets (2048 nodes)
  auto al = [](size_t v) { return (v + 255) & ~(size_t)255; };

  const size_t nn = (size_t)n;
  size_t sz_off = al((size_t)nbf * 257 * 4);
  size_t sz_y   = al(nn * 4);
  size_t sz_ds  = al(nn * 8);
  size_t sz_gc  = al(((size_t)nb1 + nbf) * 4);
  size_t fixed = sz_off + sz_y + sz_ds + sz_gc;

  // main-path capacities (exact counts + Poisson slack)
  long long mean1 = (long long)E / (nb1 > 0 ? nb1 : 1);
  long long C1ll = ((mean1 + 2048 + 1024) + 15) & ~15LL;
  long long mean2 = (long long)E / nbf;
  long long C2ll = ((mean2 + 1024) + 15) & ~15LL;
  size_t need_main = fixed + al((size_t)nb1 * C1ll * 4) + al((size_t)nbf * C2ll * 4);
  const bool main_ok = (n <= 524288) && (nb1 <= MAXNB1) && (nbf <= MAXNBF) &&
                       (C2ll <= SORT_STAGE) && (need_main <= ws_size);

  if (main_ok) {
    const int C1 = (int)C1ll, C2 = (int)C2ll;
    char* p = (char*)d_ws;
    int*    pay1  = (int*)p;    p += al((size_t)nb1 * C1 * 4);
    int*    pay2  = (int*)p;    p += al((size_t)nbf * C2 * 4);
    int*    gcur1 = (int*)p;    // nb1 + nbf contiguous
    int*    gcur2 = gcur1 + nb1;
    p += sz_gc;
    int*    off_g = (int*)p;    p += sz_off;
    float*  y     = (float*)p;  p += sz_y;
    float2* ds    = (float2*)p; p += sz_ds;

    hipMemsetAsync(gcur1, 0, ((size_t)nb1 + nbf) * 4, stream);

    int chunk = (int)(((long long)E + B1_BLOCKS - 1) / B1_BLOCKS);
    chunk = (chunk + 3) & ~3;

    k_bin1<<<B1_BLOCKS, B1_THREADS, 0, stream>>>(src, dst, E, chunk, nb1, C1,
                                                 gcur1, pay1);
    k_bin2<<<nb1 * 2, B2_THREADS, 0, stream>>>(pay1, gcur1, C1, C2, gcur2,
                                               pay2);
    k_sort<<<nbf, 256, 0, stream>>>(pay2, gcur2, C2, n, x, off_g, y);
    k_reduce1<<<nbf, 256, 0, stream>>>(pay2, off_g, C2, n, y, ds);
    k_reduce2<<<nbf, 256, 0, stream>>>(pay2, off_g, C2, n, ds, W1, b1, W2, b2,
                                       (float4*)d_out);
    return;
  }

  // ---- fallback: round-5 flat binning into fine buckets ----
  {
    double mean = (double)E / nbf;
    long long Cwant = (long long)(mean * 1.10) +
                      (long long)(FB_BLOCKS * FB_PAD / 2) + 512;
    size_t budget = ws_size > fixed ? ws_size - fixed - 4096 : 0;
    long long Cbud = (long long)(budget / ((size_t)nbf * 4));
    long long Cll = Cwant < Cbud ? Cwant : Cbud;
    if (Cll > SORT_STAGE) Cll = SORT_STAGE;
    int C = (int)(Cll & ~(long long)(FB_PAD - 1));

    char* p = (char*)d_ws;
    int*    pay2  = (int*)p;    p += al((size_t)nbf * C * 4);
    int*    gcur  = (int*)p;    p += sz_gc;
    int*    off_g = (int*)p;    p += sz_off;
    float*  y     = (float*)p;  p += sz_y;
    float2* ds    = (float2*)p; p += sz_ds;

    hipMemsetAsync(gcur, 0, (size_t)nbf * 4, stream);

    int chunk = (int)(((long long)E + FB_BLOCKS - 1) / FB_BLOCKS);
    chunk = (chunk + 3) & ~3;

    k_bin_flat<<<FB_BLOCKS, FB_THREADS, 0, stream>>>(src, dst, E, chunk, nbf,
                                                     C, gcur, pay2);
    k_sort<<<nbf, 256, 0, stream>>>(pay2, gcur, C, n, x, off_g, y);
    k_reduce1<<<nbf, 256, 0, stream>>>(pay2, off_g, C, n, y, ds);
    k_reduce2<<<nbf, 256, 0, stream>>>(pay2, off_g, C, n, ds, W1, b1, W2, b2,
                                       (float4*)d_out);
  }
}

// Round 2
// 524.022 us; speedup vs baseline: 1.1601x; 1.1601x over previous
//
#include <hip/hip_runtime.h>

// 2-layer GCNConv, N=500K, E=16M, Cin=1, Cout=4, fp32.
//
// Round-7: round-6's quad-per-node reduce removed the DS-pipe scan but
// 5x'd FETCH (gather stream thrashed L2; 498MB @ 3.2TB/s = the whole
// 155us). Revert to the edge-linear traversal (proven 97MB FETCH) and
// replace the __shfl_up segmented scan (DS pipe, ~39 ds_bpermute per 64
// edges) with a DPP segmented scan (row_shr 1/2/4/8 + row_bcast15/31)
// that runs entirely on the idle VALU pipe. DS ops per 64 edges drop
// 39 -> ~5 (one boundary shfl + boundary atomics). Payload reads are
// non-temporal to protect L2 residency of the y/ds gather arrays.

#define B1_BLOCKS 512
#define B1_THREADS 1024
#define TILE1 16384
#define B2_THREADS 1024
#define TILE2 16384
#define MAXNB1 256       // coarse buckets (2048 nodes); needs n <= 524288
#define SORT_STAGE 12032 // ints staged in LDS by k_sort; C2 <= this
// fallback (round-5 flat binning) constants
#define FB_BLOCKS 512
#define FB_THREADS 1024
#define FB_PAD 8
#define MAXNBF 2048

// ---------------- DPP segmented-scan helpers (VALU pipe, no LDS) -----------
// Inclusive segmented sum-scan over a wave64 with sorted keys m.
// row_shr:d steps (d=1,2,4,8) scan within 16-lane rows; row_bcast15
// (rows 1,3 <- lanes 15/47) then row_bcast31 (rows 2,3 <- lane 31)
// stitch rows, each add gated by key equality. bound_ctrl=1 shifts in 0
// for the value (adding 0 is always safe); masked rows get old:
// 0 for values, -1 for keys (never matches m in [0,255] or 999).

template <int CTRL, int RM, int KOLD>
__device__ __forceinline__ void seg_step1(int m, float& a) {
  const int mm = __builtin_amdgcn_update_dpp(KOLD, m, CTRL, RM, 0xf, true);
  const float f = (mm == m) ? 1.0f : 0.0f;
  const float ba = __int_as_float(
      __builtin_amdgcn_update_dpp(0, __float_as_int(a), CTRL, RM, 0xf, true));
  a = fmaf(ba, f, a);
}

template <int CTRL, int RM, int KOLD>
__device__ __forceinline__ void seg_step4(int m, float& gx, float& gy,
                                          float& gz, float& gw) {
  const int mm = __builtin_amdgcn_update_dpp(KOLD, m, CTRL, RM, 0xf, true);
  const float f = (mm == m) ? 1.0f : 0.0f;
  const float bx = __int_as_float(
      __builtin_amdgcn_update_dpp(0, __float_as_int(gx), CTRL, RM, 0xf, true));
  const float by = __int_as_float(
      __builtin_amdgcn_update_dpp(0, __float_as_int(gy), CTRL, RM, 0xf, true));
  const float bz = __int_as_float(
      __builtin_amdgcn_update_dpp(0, __float_as_int(gz), CTRL, RM, 0xf, true));
  const float bw = __int_as_float(
      __builtin_amdgcn_update_dpp(0, __float_as_int(gw), CTRL, RM, 0xf, true));
  gx = fmaf(bx, f, gx);
  gy = fmaf(by, f, gy);
  gz = fmaf(bz, f, gz);
  gw = fmaf(bw, f, gw);
}

__device__ __forceinline__ void seg_scan1(int m, float& a) {
  seg_step1<0x111, 0xf, 0>(m, a);   // row_shr:1
  seg_step1<0x112, 0xf, 0>(m, a);   // row_shr:2
  seg_step1<0x114, 0xf, 0>(m, a);   // row_shr:4
  seg_step1<0x118, 0xf, 0>(m, a);   // row_shr:8
  seg_step1<0x142, 0xa, -1>(m, a);  // row_bcast15 -> rows 1,3
  seg_step1<0x143, 0xc, -1>(m, a);  // row_bcast31 -> rows 2,3
}

__device__ __forceinline__ void seg_scan4(int m, float& gx, float& gy,
                                          float& gz, float& gw) {
  seg_step4<0x111, 0xf, 0>(m, gx, gy, gz, gw);
  seg_step4<0x112, 0xf, 0>(m, gx, gy, gz, gw);
  seg_step4<0x114, 0xf, 0>(m, gx, gy, gz, gw);
  seg_step4<0x118, 0xf, 0>(m, gx, gy, gz, gw);
  seg_step4<0x142, 0xa, -1>(m, gx, gy, gz, gw);
  seg_step4<0x143, 0xc, -1>(m, gx, gy, gz, gw);
}

// ---------------- pass 1: coarse split (LDS-staged, coalesced flush) -------
__global__ __launch_bounds__(B1_THREADS) void k_bin1(
    const int* __restrict__ src, const int* __restrict__ dst, int E,
    int chunk, int nb1, int C1, int* __restrict__ gcur1,
    int* __restrict__ pay1) {
  __shared__ int out[TILE1];
  __shared__ int hist[MAXNB1], toff[MAXNB1], wcur[MAXNB1], gb[MAXNB1];
  __shared__ int sbuf[2][MAXNB1];
  const int tid = threadIdx.x;
  const long long e0 = (long long)blockIdx.x * chunk;
  long long reml = (long long)E - e0;
  const int lim = reml < 0 ? 0 : (reml < chunk ? (int)reml : chunk);
  const int* dch = dst + e0;
  const int* sch = src + e0;

  for (int tb = 0; tb < lim; tb += TILE1) {
    const int tcnt = min(TILE1, lim - tb);
    const int nv = tcnt >> 2;
    for (int j = tid; j < MAXNB1; j += B1_THREADS) hist[j] = 0;
    __syncthreads();

    // phase A: tile histogram of coarse keys
    const int* dt = dch + tb;
    for (int k = tid; k < nv; k += B1_THREADS) {
      int4 d = reinterpret_cast<const int4*>(dt)[k];
      atomicAdd(&hist[d.x >> 11], 1);
      atomicAdd(&hist[d.y >> 11], 1);
      atomicAdd(&hist[d.z >> 11], 1);
      atomicAdd(&hist[d.w >> 11], 1);
    }
    for (int k = (nv << 2) + tid; k < tcnt; k += B1_THREADS)
      atomicAdd(&hist[dt[k] >> 11], 1);
    __syncthreads();

    // phase B: exclusive scan (256-wide) + exact global range reservation
    if (tid < MAXNB1) sbuf[0][tid] = hist[tid];
    __syncthreads();
    int pi = 0;
    for (int dd = 1; dd < MAXNB1; dd <<= 1) {
      if (tid < MAXNB1) {
        int v = sbuf[pi][tid];
        if (tid >= dd) v += sbuf[pi][tid - dd];
        sbuf[pi ^ 1][tid] = v;
      }
      pi ^= 1;
      __syncthreads();
    }
    if (tid < MAXNB1) {
      int c = hist[tid];
      int exc = sbuf[pi][tid] - c;
      toff[tid] = exc;
      wcur[tid] = exc;
      gb[tid] = c ? atomicAdd(&gcur1[tid], c) : 0;
    }
    __syncthreads();

    // phase C: rank + place packed (src<<11 | dst&2047) into LDS out
    const int* st = sch + tb;
    for (int k = tid; k < nv; k += B1_THREADS) {
      int4 d = reinterpret_cast<const int4*>(dt)[k];
      int4 s = reinterpret_cast<const int4*>(st)[k];
      int r0 = atomicAdd(&wcur[d.x >> 11], 1);
      int r1 = atomicAdd(&wcur[d.y >> 11], 1);
      int r2 = atomicAdd(&wcur[d.z >> 11], 1);
      int r3 = atomicAdd(&wcur[d.w >> 11], 1);
      out[r0] = (s.x << 11) | (d.x & 2047);
      out[r1] = (s.y << 11) | (d.y & 2047);
      out[r2] = (s.z << 11) | (d.z & 2047);
      out[r3] = (s.w << 11) | (d.w & 2047);
    }
    for (int k = (nv << 2) + tid; k < tcnt; k += B1_THREADS) {
      int d = dt[k], s = st[k];
      int r = atomicAdd(&wcur[d >> 11], 1);
      out[r] = (s << 11) | (d & 2047);
    }
    __syncthreads();

    // phase D: wave-per-bucket coalesced copy LDS -> global
    const int wv = tid >> 6, lane = tid & 63;
    for (int j = wv; j < nb1; j += 16) {
      const int c = wcur[j] - toff[j];
      if (!c) continue;
      const int gbase = gb[j];
      const long long pbase = (long long)j * C1;
      for (int q = lane; q < c; q += 64) {
        int gi = gbase + q;
        if (gi < C1) pay1[pbase + gi] = out[toff[j] + q];
      }
    }
    __syncthreads();
  }
}

// ---------------- pass 2: fine split (8 buckets per coarse) ----------------
__global__ __launch_bounds__(B2_THREADS) void k_bin2(
    const int* __restrict__ pay1, const int* __restrict__ gcur1, int C1,
    int C2, int* __restrict__ gcur2, int* __restrict__ pay2) {
  __shared__ int out[TILE2];
  __shared__ int hist[8], toff9[9], wcur[8], gb[8];
  const int cb = blockIdx.x >> 1;
  const int half = blockIdx.x & 1;
  const int tid = threadIdx.x;
  const int Lc = min(gcur1[cb], C1);
  int mid = ((Lc >> 1) + 3) & ~3;
  if (mid > Lc) mid = Lc;
  const int h0 = half ? mid : 0;
  const int h1 = half ? Lc : mid;
  const int* seg = pay1 + (long long)cb * C1;

  for (int tb = h0; tb < h1; tb += TILE2) {
    const int tcnt = min(TILE2, h1 - tb);
    const int nv = tcnt >> 2;
    if (tid < 8) hist[tid] = 0;
    __syncthreads();
    const int* pt = seg + tb;

    for (int k = tid; k < nv; k += B2_THREADS) {
      int4 p = reinterpret_cast<const int4*>(pt)[k];
      atomicAdd(&hist[(p.x >> 8) & 7], 1);
      atomicAdd(&hist[(p.y >> 8) & 7], 1);
      atomicAdd(&hist[(p.z >> 8) & 7], 1);
      atomicAdd(&hist[(p.w >> 8) & 7], 1);
    }
    for (int k = (nv << 2) + tid; k < tcnt; k += B2_THREADS)
      atomicAdd(&hist[(pt[k] >> 8) & 7], 1);
    __syncthreads();

    if (tid == 0) {
      int run = 0;
      for (int j = 0; j < 8; ++j) { toff9[j] = run; run += hist[j]; }
      toff9[8] = run;
    }
    __syncthreads();
    if (tid < 8) {
      wcur[tid] = toff9[tid];
      gb[tid] = hist[tid] ? atomicAdd(&gcur2[cb * 8 + tid], hist[tid]) : 0;
    }
    __syncthreads();

    for (int k = tid; k < nv; k += B2_THREADS) {
      int4 p = reinterpret_cast<const int4*>(pt)[k];
      out[atomicAdd(&wcur[(p.x >> 8) & 7], 1)] = ((p.x >> 11) << 8) | (p.x & 255);
      out[atomicAdd(&wcur[(p.y >> 8) & 7], 1)] = ((p.y >> 11) << 8) | (p.y & 255);
      out[atomicAdd(&wcur[(p.z >> 8) & 7], 1)] = ((p.z >> 11) << 8) | (p.z & 255);
      out[atomicAdd(&wcur[(p.w >> 8) & 7], 1)] = ((p.w >> 11) << 8) | (p.w & 255);
    }
    for (int k = (nv << 2) + tid; k < tcnt; k += B2_THREADS) {
      int p = pt[k];
      out[atomicAdd(&wcur[(p >> 8) & 7], 1)] = ((p >> 11) << 8) | (p & 255);
    }
    __syncthreads();

    const int total = toff9[8];
    for (int q = tid; q < total; q += B2_THREADS) {
      int j = (q >= toff9[4]) ? 4 : 0;
      j += (q >= toff9[j + 2]) ? 2 : 0;
      j += (q >= toff9[j + 1]) ? 1 : 0;
      int o = gb[j] + (q - toff9[j]);
      if (o < C2) pay2[(long long)(cb * 8 + j) * C2 + o] = out[q];
    }
    __syncthreads();
  }
}

// ---------------- fallback flat binning (round-5, proven) ------------------
__global__ __launch_bounds__(FB_THREADS) void k_bin_flat(
    const int* __restrict__ src, const int* __restrict__ dst, int E,
    int chunk, int nbf, int C, int* __restrict__ gcur,
    int* __restrict__ payload) {
  __shared__ int hist[MAXNBF];
  __shared__ int lbase[MAXNBF];
  const int tid = threadIdx.x;
  const long long e0 = (long long)blockIdx.x * chunk;
  long long rem = (long long)E - e0;
  int lim = rem < 0 ? 0 : (rem < chunk ? (int)rem : chunk);
  for (int j = tid; j < nbf; j += FB_THREADS) hist[j] = 0;
  __syncthreads();
  const int* dch = dst + e0;
  const int* sch = src + e0;
  const int nv = lim >> 2;
  for (int k = tid; k < nv; k += FB_THREADS) {
    int4 d = reinterpret_cast<const int4*>(dch)[k];
    atomicAdd(&hist[d.x >> 8], 1);
    atomicAdd(&hist[d.y >> 8], 1);
    atomicAdd(&hist[d.z >> 8], 1);
    atomicAdd(&hist[d.w >> 8], 1);
  }
  for (int k = (nv << 2) + tid; k < lim; k += FB_THREADS)
    atomicAdd(&hist[dch[k] >> 8], 1);
  __syncthreads();
  for (int j = tid; j < nbf; j += FB_THREADS) {
    int c = hist[j];
    lbase[j] = c ? atomicAdd(&gcur[j], (c + FB_PAD - 1) & ~(FB_PAD - 1)) : 0;
    hist[j] = 0;
  }
  __syncthreads();
  for (int k = tid; k < nv; k += FB_THREADS) {
    int4 d = reinterpret_cast<const int4*>(dch)[k];
    int4 s = reinterpret_cast<const int4*>(sch)[k];
    int b0 = d.x >> 8, b1 = d.y >> 8, b2 = d.z >> 8, b3 = d.w >> 8;
    int r0 = atomicAdd(&hist[b0], 1) + lbase[b0];
    int r1 = atomicAdd(&hist[b1], 1) + lbase[b1];
    int r2 = atomicAdd(&hist[b2], 1) + lbase[b2];
    int r3 = atomicAdd(&hist[b3], 1) + lbase[b3];
    if (r0 < C) payload[(long long)b0 * C + r0] = (s.x << 8) | (d.x & 255);
    if (r1 < C) payload[(long long)b1 * C + r1] = (s.y << 8) | (d.y & 255);
    if (r2 < C) payload[(long long)b2 * C + r2] = (s.z << 8) | (d.z & 255);
    if (r3 < C) payload[(long long)b3 * C + r3] = (s.w << 8) | (d.w & 255);
  }
  for (int k = (nv << 2) + tid; k < lim; k += FB_THREADS) {
    int d = dch[k], s = sch[k];
    int bk = d >> 8;
    int r = atomicAdd(&hist[bk], 1) + lbase[bk];
    if (r < C) payload[(long long)bk * C + r] = (s << 8) | (d & 255);
  }
  __syncthreads();
  for (int j = tid; j < nbf; j += FB_THREADS) {
    int c = hist[j];
    if (c) {
      int pc = (c + FB_PAD - 1) & ~(FB_PAD - 1);
      long long base = (long long)j * C;
      for (int k = lbase[j] + c; k < lbase[j] + pc; ++k)
        if (k < C) payload[base + k] = -1;
    }
  }
}

// ---------------- per-bucket counting sort to node order -------------------
__global__ __launch_bounds__(256) void k_sort(
    int* __restrict__ payload, const int* __restrict__ gcur, int C,
    int n, const float* __restrict__ x,
    int* __restrict__ off_g, float* __restrict__ y) {
  __shared__ int stage[SORT_STAGE];
  __shared__ int hist[256];
  __shared__ int sbuf[2][256];
  __shared__ int cur[256];
  const int b = blockIdx.x, t = threadIdx.x;
  hist[t] = 0;
  __syncthreads();
  int* seg = payload + (long long)b * C;
  const int L = min(gcur[b], C);
  const int nv = L >> 2;
#pragma unroll 2
  for (int k = t; k < nv; k += 256) {
    int4 p = reinterpret_cast<const int4*>(seg)[k];
    reinterpret_cast<int4*>(stage)[k] = p;
    if (p.x >= 0) atomicAdd(&hist[p.x & 255], 1);
    if (p.y >= 0) atomicAdd(&hist[p.y & 255], 1);
    if (p.z >= 0) atomicAdd(&hist[p.z & 255], 1);
    if (p.w >= 0) atomicAdd(&hist[p.w & 255], 1);
  }
  for (int k = (nv << 2) + t; k < L; k += 256) {
    int p = seg[k];
    stage[k] = p;
    if (p >= 0) atomicAdd(&hist[p & 255], 1);
  }
  __syncthreads();
  sbuf[0][t] = hist[t];
  __syncthreads();
  int pi = 0;
  for (int d = 1; d < 256; d <<= 1) {
    int v = sbuf[pi][t];
    if (t >= d) v += sbuf[pi][t - d];
    sbuf[pi ^ 1][t] = v;
    pi ^= 1;
    __syncthreads();
  }
  const int inc = sbuf[pi][t];
  const int exc = inc - hist[t];
  cur[t] = exc;
  off_g[b * 257 + t] = exc;
  if (t == 255) off_g[b * 257 + 256] = inc;
  const int i = (b << 8) + t;
  if (i < n) y[i] = rsqrtf((float)(hist[t] + 1)) * x[i];
  __syncthreads();
#pragma unroll 4
  for (int k = t; k < L; k += 256) {
    int p = stage[k];
    if (p >= 0) {
      int pos = atomicAdd(&cur[p & 255], 1);
      seg[pos] = p;
    }
  }
}

// ---------------- layer-1 segmented sum -> ds = (dinv, s) ------------------
__global__ __launch_bounds__(256) void k_reduce1(
    const int* __restrict__ payload, const int* __restrict__ off_g, int C,
    int n, const float* __restrict__ y, float2* __restrict__ ds) {
  __shared__ float S[256];
  const int b = blockIdx.x, t = threadIdx.x;
  S[t] = 0.0f;
  __syncthreads();
  const int L = off_g[b * 257 + 256];
  const int* seg = payload + (long long)b * C;
  const int lane = t & 63;
  for (int base = t - lane; base < L; base += 256) {
    int k = base + lane;
    bool valid = k < L;
    int p = 0;
    if (valid) p = __builtin_nontemporal_load(seg + k);
    int m = valid ? (p & 255) : 999;
    float v = valid ? y[p >> 8] : 0.0f;
    seg_scan1(m, v);  // DPP segmented scan (VALU pipe)
    int mn = __shfl_down(m, 1, 64);
    if ((lane == 63 || mn != m) && m < 256) atomicAdd(&S[m], v);
  }
  __syncthreads();
  const int i = (b << 8) + t;
  if (i < n) {
    int deg = off_g[b * 257 + t + 1] - off_g[b * 257 + t];
    float r = rsqrtf((float)(deg + 1));
    ds[i] = make_float2(r, r * (S[t] + y[i]));
  }
}

// ---------------- layer-2: gather ds, compute message, segmented sum -------
__global__ __launch_bounds__(256) void k_reduce2(
    const int* __restrict__ payload, const int* __restrict__ off_g, int C,
    int n, const float2* __restrict__ ds,
    const float* __restrict__ W1, const float* __restrict__ b1,
    const float* __restrict__ W2, const float* __restrict__ b2,
    float4* __restrict__ out) {
  __shared__ float S0[256], S1[256], S2[256], S3[256];
  const int b = blockIdx.x, t = threadIdx.x;
  S0[t] = 0.f; S1[t] = 0.f; S2[t] = 0.f; S3[t] = 0.f;
  __syncthreads();
  const float w10 = W1[0], w11 = W1[1], w12 = W1[2], w13 = W1[3];
  const float c10 = b1[0], c11 = b1[1], c12 = b1[2], c13 = b1[3];
  float w2[16];
#pragma unroll
  for (int k = 0; k < 16; ++k) w2[k] = W2[k];

  const int L = off_g[b * 257 + 256];
  const int* seg = payload + (long long)b * C;
  const int lane = t & 63;
  for (int base = t - lane; base < L; base += 256) {
    int k = base + lane;
    bool valid = k < L;
    int p = 0;
    if (valid) p = __builtin_nontemporal_load(seg + k);
    int m = valid ? (p & 255) : 999;
    float2 v = valid ? ds[p >> 8] : make_float2(0.f, 0.f);
    float r = valid ? v.x : 0.0f;  // r=0 zeroes the whole message
    float s = v.y;
    float h0 = fmaxf(fmaf(s, w10, c10), 0.f);
    float h1 = fmaxf(fmaf(s, w11, c11), 0.f);
    float h2 = fmaxf(fmaf(s, w12, c12), 0.f);
    float h3 = fmaxf(fmaf(s, w13, c13), 0.f);
    float gx = r * (h0 * w2[0] + h1 * w2[4] + h2 * w2[8]  + h3 * w2[12]);
    float gy = r * (h0 * w2[1] + h1 * w2[5] + h2 * w2[9]  + h3 * w2[13]);
    float gz = r * (h0 * w2[2] + h1 * w2[6] + h2 * w2[10] + h3 * w2[14]);
    float gw = r * (h0 * w2[3] + h1 * w2[7] + h2 * w2[11] + h3 * w2[15]);
    seg_scan4(m, gx, gy, gz, gw);  // DPP segmented scan (VALU pipe)
    int mn = __shfl_down(m, 1, 64);
    if ((lane == 63 || mn != m) && m < 256) {
      atomicAdd(&S0[m], gx);
      atomicAdd(&S1[m], gy);
      atomicAdd(&S2[m], gz);
      atomicAdd(&S3[m], gw);
    }
  }
  __syncthreads();
  const int i = (b << 8) + t;
  if (i < n) {
    float2 v = ds[i];
    float r = v.x, s = v.y;
    float h0 = fmaxf(fmaf(s, w10, c10), 0.f);
    float h1 = fmaxf(fmaf(s, w11, c11), 0.f);
    float h2 = fmaxf(fmaf(s, w12, c12), 0.f);
    float h3 = fmaxf(fmaf(s, w13, c13), 0.f);
    float gx = r * (h0 * w2[0] + h1 * w2[4] + h2 * w2[8]  + h3 * w2[12]);
    float gy = r * (h0 * w2[1] + h1 * w2[5] + h2 * w2[9]  + h3 * w2[13]);
    float gz = r * (h0 * w2[2] + h1 * w2[6] + h2 * w2[10] + h3 * w2[14]);
    float gw = r * (h0 * w2[3] + h1 * w2[7] + h2 * w2[11] + h3 * w2[15]);
    out[i] = make_float4(b2[0] + r * (S0[t] + gx),
                         b2[1] + r * (S1[t] + gy),
                         b2[2] + r * (S2[t] + gz),
                         b2[3] + r * (S3[t] + gw));
  }
}

extern "C" void kernel_launch(void* const* d_in, const int* in_sizes, int n_in,
                              void* d_out, int out_size, void* d_ws, size_t ws_size,
                              hipStream_t stream) {
  const float* x  = (const float*)d_in[0];
  const int*   ei = (const int*)d_in[1];
  const float* W1 = (const float*)d_in[2];
  const float* b1 = (const float*)d_in[3];
  const float* W2 = (const float*)d_in[4];
  const float* b2 = (const float*)d_in[5];

  const int n = in_sizes[0];
  const int E = in_sizes[1] / 2;
  const int* src = ei;
  const int* dst = ei + E;

  const int nbf = (n + 255) >> 8;    // fine buckets (256 nodes)
  const int nb1 = (n + 2047) >> 11;  // coarse buckets (2048 nodes)
  auto al = [](size_t v) { return (v + 255) & ~(size_t)255; };

  const size_t nn = (size_t)n;
  size_t sz_off = al((size_t)nbf * 257 * 4);
  size_t sz_y   = al(nn * 4);
  size_t sz_ds  = al(nn * 8);
  size_t sz_gc  = al(((size_t)nb1 + nbf) * 4);
  size_t fixed = sz_off + sz_y + sz_ds + sz_gc;

  // main-path capacities (exact counts + Poisson slack)
  long long mean1 = (long long)E / (nb1 > 0 ? nb1 : 1);
  long long C1ll = ((mean1 + 2048 + 1024) + 15) & ~15LL;
  long long mean2 = (long long)E / nbf;
  long long C2ll = ((mean2 + 1024) + 15) & ~15LL;
  size_t need_main = fixed + al((size_t)nb1 * C1ll * 4) + al((size_t)nbf * C2ll * 4);
  const bool main_ok = (n <= 524288) && (nb1 <= MAXNB1) && (nbf <= MAXNBF) &&
                       (C2ll <= SORT_STAGE) && (need_main <= ws_size);

  if (main_ok) {
    const int C1 = (int)C1ll, C2 = (int)C2ll;
    char* p = (char*)d_ws;
    int*    pay1  = (int*)p;    p += al((size_t)nb1 * C1 * 4);
    int*    pay2  = (int*)p;    p += al((size_t)nbf * C2 * 4);
    int*    gcur1 = (int*)p;    // nb1 + nbf contiguous
    int*    gcur2 = gcur1 + nb1;
    p += sz_gc;
    int*    off_g = (int*)p;    p += sz_off;
    float*  y     = (float*)p;  p += sz_y;
    float2* ds    = (float2*)p; p += sz_ds;

    hipMemsetAsync(gcur1, 0, ((size_t)nb1 + nbf) * 4, stream);

    int chunk = (int)(((long long)E + B1_BLOCKS - 1) / B1_BLOCKS);
    chunk = (chunk + 3) & ~3;

    k_bin1<<<B1_BLOCKS, B1_THREADS, 0, stream>>>(src, dst, E, chunk, nb1, C1,
                                                 gcur1, pay1);
    k_bin2<<<nb1 * 2, B2_THREADS, 0, stream>>>(pay1, gcur1, C1, C2, gcur2,
                                               pay2);
    k_sort<<<nbf, 256, 0, stream>>>(pay2, gcur2, C2, n, x, off_g, y);
    k_reduce1<<<nbf, 256, 0, stream>>>(pay2, off_g, C2, n, y, ds);
    k_reduce2<<<nbf, 256, 0, stream>>>(pay2, off_g, C2, n, ds, W1, b1, W2, b2,
                                       (float4*)d_out);
    return;
  }

  // ---- fallback: round-5 flat binning into fine buckets ----
  {
    double mean = (double)E / nbf;
    long long Cwant = (long long)(mean * 1.10) +
                      (long long)(FB_BLOCKS * FB_PAD / 2) + 512;
    size_t budget = ws_size > fixed ? ws_size - fixed - 4096 : 0;
    long long Cbud = (long long)(budget / ((size_t)nbf * 4));
    long long Cll = Cwant < Cbud ? Cwant : Cbud;
    if (Cll > SORT_STAGE) Cll = SORT_STAGE;
    int C = (int)(Cll & ~(long long)(FB_PAD - 1));

    char* p = (char*)d_ws;
    int*    pay2  = (int*)p;    p += al((size_t)nbf * C * 4);
    int*    gcur  = (int*)p;    p += sz_gc;
    int*    off_g = (int*)p;    p += sz_off;
    float*  y     = (float*)p;  p += sz_y;
    float2* ds    = (float2*)p; p += sz_ds;

    hipMemsetAsync(gcur, 0, (size_t)nbf * 4, stream);

    int chunk = (int)(((long long)E + FB_BLOCKS - 1) / FB_BLOCKS);
    chunk = (chunk + 3) & ~3;

    k_bin_flat<<<FB_BLOCKS, FB_THREADS, 0, stream>>>(src, dst, E, chunk, nbf,
                                                     C, gcur, pay2);
    k_sort<<<nbf, 256, 0, stream>>>(pay2, gcur, C, n, x, off_g, y);
    k_reduce1<<<nbf, 256, 0, stream>>>(pay2, off_g, C, n, y, ds);
    k_reduce2<<<nbf, 256, 0, stream>>>(pay2, off_g, C, n, ds, W1, b1, W2, b2,
                                       (float4*)d_out);
  }
}